// Round 7
// baseline (91.504 us; speedup 1.0000x reference)
//
#include <hip/hip_runtime.h>

// SIMcLoss: x [8192, 256] fp32 -> scalar.
// loss = (||Xn^T Xn||_F^2 - n)/(n^2 - n) on the 256x256 Gram matrix.
// SINGLE dispatch (160 blocks x 512 thr), no grid barriers, ticket-chained:
//   phase N: block computes inv-norms of its own 512-row chunk -> LDS
//   phase A: bf16(RNE) MFMA Gram tile (10 sym pairs x 16 K-chunks),
//            plain coalesced slab store (no atomics on bulk data)
//   phase B: per-pair ticket -> last chunk-block of each pair reduces its
//            16 slabs (weight, square), atomicAdd(S), global ticket -> loss.
// Plus one 64-byte memset node for control words.
#define D 256
#define TILE 64
#define NPAIRS 10
#define CHUNK 512
#define NCHUNK 16
#define NBLK 160
#define EPS 1e-8f

typedef __attribute__((ext_vector_type(8))) short bf16x8;
typedef __attribute__((ext_vector_type(4))) float f32x4;

__device__ __forceinline__ void pair_decode(int p, int& ta, int& tb) {
  if (p < 4)      { ta = 0; tb = p; }
  else if (p < 7) { ta = 1; tb = p - 3; }
  else if (p < 9) { ta = 2; tb = p - 5; }
  else            { ta = 3; tb = 3; }
}

// swizzled short-index into Xt[col][64 rows] (row-stride 64 shorts = 128 B).
// XOR bits 3..5 of row with g(col): b128 frag reads ~2-way, b64 writes 4-way.
__device__ __forceinline__ int swz(int col, int r) {
  int g = ((col >> 2) & 7) ^ ((col & 3) << 1);
  return col * 64 + (r ^ (g << 3));
}

// round-to-nearest-even fp32 -> bf16 (truncation would bias S)
__device__ __forceinline__ unsigned short rne_bf16(float f) {
  unsigned u = __float_as_uint(f);
  return (unsigned short)((u + 0x7fffu + ((u >> 16) & 1u)) >> 16);
}

__global__ __launch_bounds__(512) void k_all(
    const float* __restrict__ x, float* __restrict__ slabs,
    float* __restrict__ S, unsigned int* __restrict__ pair_cnt,
    unsigned int* __restrict__ gcnt, float* __restrict__ out, int N) {
  const int bx = blockIdx.x;
  const int pair = bx >> 4, chunk = bx & (NCHUNK - 1);
  int ta, tb; pair_decode(pair, ta, tb);
  const bool same = (ta == tb);
  const int row0 = chunk * CHUNK;
  const int tid = threadIdx.x;
  const int w = tid >> 6, lane = tid & 63;

  __shared__ short X[128 * 64];     // [col][row], cols 0..63=A, 64..127=B
  __shared__ float inv_s[CHUNK];
  __shared__ float red[8];
  __shared__ unsigned int tkt;

  // ---- phase N: own-chunk row inverse norms (one wave per row) ----
  #pragma unroll 4
  for (int i = 0; i < CHUNK / 8; ++i) {
    const int rr = w * (CHUNK / 8) + i;
    const float4 v =
        reinterpret_cast<const float4*>(x + (size_t)(row0 + rr) * D)[lane];
    float s = v.x * v.x + v.y * v.y + v.z * v.z + v.w * v.w;
    #pragma unroll
    for (int o = 32; o > 0; o >>= 1) s += __shfl_xor(s, o);
    if (lane == 0) inv_s[rr] = 1.0f / fmaxf(sqrtf(s), EPS);
  }
  __syncthreads();

  // ---- phase A: staging + MFMA (round-5 validated structure) ----
  const int lcb = same ? 4 : 5;                 // log2(col-blocks)
  const int ntask = 16 << lcb;                  // 256 or 512
  const bool active = tid < ntask;
  const int c0 = (tid & ((1 << lcb) - 1)) << 2; // LDS col base
  const int r0 = (active ? (tid >> lcb) : 0) << 2;
  const int gc0 = (c0 < TILE) ? ta * TILE + c0 : tb * TILE + (c0 - TILE);

  const int i0 = (w >> 1) << 4;                 // 0,16,32,48
  const int j0 = (w & 1) << 5;                  // 0,32
  const int lm = lane & 15, lk = lane >> 4;
  const int bbase = same ? 0 : 64;

  f32x4 zero = {0.f, 0.f, 0.f, 0.f};
  f32x4 acc[2] = {zero, zero};

  float4 pv[4];
  if (active) {
    const float* xb = x + (size_t)(row0 + r0) * D + gc0;
    #pragma unroll
    for (int jj = 0; jj < 4; ++jj)
      pv[jj] = *reinterpret_cast<const float4*>(xb + (size_t)jj * D);
  }

  const int NSUB = CHUNK / 64;                  // 8
  for (int s = 0; s < NSUB; ++s) {
    if (active) {
      unsigned short hh[4][4];
      #pragma unroll
      for (int jj = 0; jj < 4; ++jj) {
        const float iv = inv_s[s * 64 + r0 + jj];
        const float vv[4] = {pv[jj].x, pv[jj].y, pv[jj].z, pv[jj].w};
        #pragma unroll
        for (int cc = 0; cc < 4; ++cc)
          hh[jj][cc] = rne_bf16(vv[cc] * iv);
      }
      #pragma unroll
      for (int cc = 0; cc < 4; ++cc)
        *reinterpret_cast<ushort4*>(&X[swz(c0 + cc, r0)]) =
            make_ushort4(hh[0][cc], hh[1][cc], hh[2][cc], hh[3][cc]);
      if (s + 1 < NSUB) {                       // prefetch next sub-chunk
        const float* xb = x + (size_t)(row0 + (s + 1) * 64 + r0) * D + gc0;
        #pragma unroll
        for (int jj = 0; jj < 4; ++jj)
          pv[jj] = *reinterpret_cast<const float4*>(xb + (size_t)jj * D);
      }
    }
    __syncthreads();
    #pragma unroll
    for (int rr = 0; rr < 64; rr += 32) {
      const int rbase = rr + lk * 8;
      bf16x8 A  = *reinterpret_cast<const bf16x8*>(&X[swz(i0 + lm, rbase)]);
      bf16x8 B0 = *reinterpret_cast<const bf16x8*>(&X[swz(bbase + j0 + lm, rbase)]);
      bf16x8 B1 = *reinterpret_cast<const bf16x8*>(&X[swz(bbase + j0 + 16 + lm, rbase)]);
      acc[0] = __builtin_amdgcn_mfma_f32_16x16x32_bf16(A, B0, acc[0], 0, 0, 0);
      acc[1] = __builtin_amdgcn_mfma_f32_16x16x32_bf16(A, B1, acc[1], 0, 0, 0);
    }
    __syncthreads();
  }

  // slab store (plain, coalesced); C/D layout: col=lane&15, row=(lane>>4)*4+reg
  float* slab = slabs + (size_t)bx * (TILE * TILE);
  #pragma unroll
  for (int jt = 0; jt < 2; ++jt)
    #pragma unroll
    for (int rg = 0; rg < 4; ++rg)
      slab[(i0 + lk * 4 + rg) * TILE + (j0 + jt * 16 + lm)] = acc[jt][rg];

  // ---- phase B: per-pair ticket; last chunk-block reduces the pair ----
  __threadfence();                               // release slab stores
  __syncthreads();
  if (tid == 0)
    tkt = __hip_atomic_fetch_add(&pair_cnt[pair], 1u, __ATOMIC_ACQ_REL,
                                 __HIP_MEMORY_SCOPE_AGENT);
  __syncthreads();
  if (tkt != (unsigned)(NCHUNK - 1)) return;     // not last -> done

  const float* pbase = slabs + (size_t)pair * NCHUNK * (TILE * TILE);
  const bool diag = same;
  float part = 0.f;
  #pragma unroll
  for (int t4 = tid; t4 < (TILE * TILE / 4); t4 += 512) {  // 2 iters
    float tx = 0.f, ty = 0.f, tz = 0.f, tw = 0.f;
    #pragma unroll
    for (int c = 0; c < NCHUNK; ++c) {
      const float4 v = reinterpret_cast<const float4*>(
          pbase + (size_t)c * (TILE * TILE))[t4];
      tx += v.x; ty += v.y; tz += v.z; tw += v.w;
    }
    part += tx * tx + ty * ty + tz * tz + tw * tw;
  }
  part *= diag ? 1.f : 2.f;
  #pragma unroll
  for (int o = 32; o > 0; o >>= 1) part += __shfl_xor(part, o);
  if (lane == 0) red[w] = part;
  __syncthreads();
  if (tid == 0) {
    float blk = 0.f;
    #pragma unroll
    for (int q = 0; q < 8; ++q) blk += red[q];
    atomicAdd(S, blk);
    __threadfence();
    unsigned int old = __hip_atomic_fetch_add(gcnt, 1u, __ATOMIC_ACQ_REL,
                                              __HIP_MEMORY_SCOPE_AGENT);
    if (old == (unsigned)(NPAIRS - 1)) {
      float Sv = __hip_atomic_load(S, __ATOMIC_RELAXED,
                                   __HIP_MEMORY_SCOPE_AGENT);
      float nf = (float)N;
      out[0] = (Sv - nf) / (nf * nf - nf);
    }
  }
}

extern "C" void kernel_launch(void* const* d_in, const int* in_sizes, int n_in,
                              void* d_out, int out_size, void* d_ws, size_t ws_size,
                              hipStream_t stream) {
  const float* x = (const float*)d_in[0];
  float* out = (float*)d_out;
  const int N = in_sizes[0] / D;       // 8192

  // ws layout (floats): ctrl[64] (S, gcnt, pair_cnt[10]) | slabs[160*4096]
  float* ctrl = (float*)d_ws;
  float* S = ctrl;
  unsigned int* gcnt = (unsigned int*)(ctrl + 1);
  unsigned int* pair_cnt = (unsigned int*)(ctrl + 2);
  float* slabs = ctrl + 64;

  hipMemsetAsync(ctrl, 0, 64, stream);           // S, gcnt, pair_cnt[10]
  k_all<<<dim3(NBLK), dim3(512), 0, stream>>>(
      x, slabs, S, pair_cnt, gcnt, out, N);
}

// Round 8
// 41.017 us; speedup vs baseline: 2.2309x; 2.2309x over previous
//
#include <hip/hip_runtime.h>

// SIMcLoss: x [8192, 256] fp32 -> scalar.
// loss = (||Xn^T Xn||_F^2 - n)/(n^2 - n) on the 256x256 Gram matrix.
// Two dispatches (cross-block hand-off ONLY at the kernel boundary —
// in-kernel device-scope fences proved catastrophic in rounds 6/7):
//   k_gram : per-block own-chunk inv-norms (LDS) + bf16(RNE) MFMA Gram
//            tiles (10 sym pairs x 16 K-chunks, double-buffered LDS,
//            1 barrier/sub-chunk), coalesced slab store. Zeroes S/cnt.
//   k_reduce: per-element chunk-sum, weight, square, block reduce,
//            160 S-atomics, last-block ticket writes the loss.
#define D 256
#define TILE 64
#define NPAIRS 10
#define CHUNK 512
#define NCHUNK 16
#define EPS 1e-8f

typedef __attribute__((ext_vector_type(8))) short bf16x8;
typedef __attribute__((ext_vector_type(4))) float f32x4;

__device__ __forceinline__ void pair_decode(int p, int& ta, int& tb) {
  if (p < 4)      { ta = 0; tb = p; }
  else if (p < 7) { ta = 1; tb = p - 3; }
  else if (p < 9) { ta = 2; tb = p - 5; }
  else            { ta = 3; tb = 3; }
}

// swizzled short-index into Xt[col][64 rows] (row-stride 64 shorts = 128 B).
// XOR bits 3..5 of row with g(col): b128 frag reads ~2-way, b64 writes 4-way.
__device__ __forceinline__ int swz(int col, int r) {
  int g = ((col >> 2) & 7) ^ ((col & 3) << 1);
  return col * 64 + (r ^ (g << 3));
}

// round-to-nearest-even fp32 -> bf16 (truncation would bias S)
__device__ __forceinline__ unsigned short rne_bf16(float f) {
  unsigned u = __float_as_uint(f);
  return (unsigned short)((u + 0x7fffu + ((u >> 16) & 1u)) >> 16);
}

// ---------------------------------------------------------------------------
// Kernel 1: norms + Gram tiles. grid (NPAIRS, NCHUNK), 512 threads.
// ---------------------------------------------------------------------------
__global__ __launch_bounds__(512) void k_gram(
    const float* __restrict__ x, float* __restrict__ slabs,
    float* __restrict__ S, unsigned int* __restrict__ cnt) {
  int ta, tb; pair_decode(blockIdx.x, ta, tb);
  const bool same = (ta == tb);
  const int row0 = blockIdx.y * CHUNK;
  const int tid = threadIdx.x;
  const int w = tid >> 6, lane = tid & 63;

  if (blockIdx.x == 0 && blockIdx.y == 0 && tid == 0) { *S = 0.f; *cnt = 0u; }

  __shared__ short X[2][128 * 64];  // double-buffered [col][row] bf16 tile
  __shared__ float inv_s[CHUNK];

  // ---- phase N: own-chunk inv-norms; wave w: rows w*64..+63, 8 in flight --
  #pragma unroll
  for (int g = 0; g < 8; ++g) {
    float4 v[8];
    #pragma unroll
    for (int j = 0; j < 8; ++j)
      v[j] = reinterpret_cast<const float4*>(
          x + (size_t)(row0 + w * 64 + g * 8 + j) * D)[lane];
    #pragma unroll
    for (int j = 0; j < 8; ++j) {
      float s = v[j].x * v[j].x + v[j].y * v[j].y +
                v[j].z * v[j].z + v[j].w * v[j].w;
      #pragma unroll
      for (int o = 32; o > 0; o >>= 1) s += __shfl_xor(s, o);
      if (lane == 0)
        inv_s[w * 64 + g * 8 + j] = 1.0f / fmaxf(sqrtf(s), EPS);
    }
  }
  __syncthreads();

  // ---- phase A: staging + MFMA (round-5 validated, now double-buffered) --
  const int lcb = same ? 4 : 5;                 // log2(col-blocks)
  const int ntask = 16 << lcb;                  // 256 or 512
  const bool active = tid < ntask;
  const int c0 = (tid & ((1 << lcb) - 1)) << 2; // LDS col base
  const int r0 = (active ? (tid >> lcb) : 0) << 2;
  const int gc0 = (c0 < TILE) ? ta * TILE + c0 : tb * TILE + (c0 - TILE);

  const int i0 = (w >> 1) << 4;                 // 0,16,32,48
  const int j0 = (w & 1) << 5;                  // 0,32
  const int lm = lane & 15, lk = lane >> 4;
  const int bbase = same ? 0 : 64;

  f32x4 zero = {0.f, 0.f, 0.f, 0.f};
  f32x4 acc[2] = {zero, zero};

  float4 pv[4];
  if (active) {
    const float* xb = x + (size_t)(row0 + r0) * D + gc0;
    #pragma unroll
    for (int jj = 0; jj < 4; ++jj)
      pv[jj] = *reinterpret_cast<const float4*>(xb + (size_t)jj * D);
  }

  const int NSUB = CHUNK / 64;                  // 8
  for (int s = 0; s < NSUB; ++s) {
    short* Xb = X[s & 1];
    if (active) {
      unsigned short hh[4][4];
      #pragma unroll
      for (int jj = 0; jj < 4; ++jj) {
        const float iv = inv_s[s * 64 + r0 + jj];
        const float vv[4] = {pv[jj].x, pv[jj].y, pv[jj].z, pv[jj].w};
        #pragma unroll
        for (int cc = 0; cc < 4; ++cc)
          hh[jj][cc] = rne_bf16(vv[cc] * iv);
      }
      #pragma unroll
      for (int cc = 0; cc < 4; ++cc)
        *reinterpret_cast<ushort4*>(&Xb[swz(c0 + cc, r0)]) =
            make_ushort4(hh[0][cc], hh[1][cc], hh[2][cc], hh[3][cc]);
      if (s + 1 < NSUB) {                       // prefetch next sub-chunk
        const float* xb = x + (size_t)(row0 + (s + 1) * 64 + r0) * D + gc0;
        #pragma unroll
        for (int jj = 0; jj < 4; ++jj)
          pv[jj] = *reinterpret_cast<const float4*>(xb + (size_t)jj * D);
      }
    }
    __syncthreads();                            // one barrier per sub-chunk
    #pragma unroll
    for (int rr = 0; rr < 64; rr += 32) {
      const int rbase = rr + lk * 8;
      bf16x8 A  = *reinterpret_cast<const bf16x8*>(&Xb[swz(i0 + lm, rbase)]);
      bf16x8 B0 = *reinterpret_cast<const bf16x8*>(&Xb[swz(bbase + j0 + lm, rbase)]);
      bf16x8 B1 = *reinterpret_cast<const bf16x8*>(&Xb[swz(bbase + j0 + 16 + lm, rbase)]);
      acc[0] = __builtin_amdgcn_mfma_f32_16x16x32_bf16(A, B0, acc[0], 0, 0, 0);
      acc[1] = __builtin_amdgcn_mfma_f32_16x16x32_bf16(A, B1, acc[1], 0, 0, 0);
    }
  }

  // slab store; C/D layout (m89): col = lane&15, row = (lane>>4)*4 + reg
  float* slab = slabs +
      ((size_t)blockIdx.x * NCHUNK + blockIdx.y) * (TILE * TILE);
  #pragma unroll
  for (int jt = 0; jt < 2; ++jt)
    #pragma unroll
    for (int rg = 0; rg < 4; ++rg)
      slab[(i0 + lk * 4 + rg) * TILE + (j0 + jt * 16 + lm)] = acc[jt][rg];
}

// ---------------------------------------------------------------------------
// Kernel 2: reduce. 160 blocks x 256 threads; one G element per thread:
// sum NCHUNK slab partials (coalesced), weight, square, block-reduce,
// atomicAdd(S) per block, last-block ticket writes the loss.
// ---------------------------------------------------------------------------
__global__ __launch_bounds__(256) void k_reduce(
    const float* __restrict__ slabs, float* __restrict__ S,
    unsigned int* __restrict__ cnt, float* __restrict__ out,
    int N, int nblocks) {
  const int g = blockIdx.x * 256 + threadIdx.x;
  const int p = g >> 12;                        // pair 0..9
  const int e = g & 4095;                       // element in 64x64 tile
  const float* base = slabs + (size_t)p * NCHUNK * (TILE * TILE) + e;
  float tot = 0.f;
  #pragma unroll
  for (int c = 0; c < NCHUNK; ++c) tot += base[(size_t)c * (TILE * TILE)];
  const bool diag = (p == 0) | (p == 4) | (p == 7) | (p == 9);
  float part = (diag ? 1.f : 2.f) * tot * tot;
  #pragma unroll
  for (int o = 32; o > 0; o >>= 1) part += __shfl_xor(part, o);
  __shared__ float red[4];
  int lane = threadIdx.x & 63, w = threadIdx.x >> 6;
  if (lane == 0) red[w] = part;
  __syncthreads();
  if (threadIdx.x == 0) {
    float blk = red[0] + red[1] + red[2] + red[3];
    atomicAdd(S, blk);
    __threadfence();
    unsigned int old = atomicAdd(cnt, 1u);
    if (old == (unsigned int)(nblocks - 1)) {
      float Sv = __hip_atomic_load(S, __ATOMIC_RELAXED,
                                   __HIP_MEMORY_SCOPE_AGENT);
      float nf = (float)N;
      out[0] = (Sv - nf) / (nf * nf - nf);
    }
  }
}

extern "C" void kernel_launch(void* const* d_in, const int* in_sizes, int n_in,
                              void* d_out, int out_size, void* d_ws, size_t ws_size,
                              hipStream_t stream) {
  const float* x = (const float*)d_in[0];
  float* out = (float*)d_out;
  const int N = in_sizes[0] / D;       // 8192

  // ws layout (floats): ctrl[64] (S, cnt) | slabs[160*4096]
  float* ctrl = (float*)d_ws;
  float* S = ctrl;
  unsigned int* cnt = (unsigned int*)(ctrl + 1);
  float* slabs = ctrl + 64;

  k_gram<<<dim3(NPAIRS, NCHUNK), dim3(512), 0, stream>>>(x, slabs, S, cnt);
  const int nb = NPAIRS * (TILE * TILE / 256);  // 160
  k_reduce<<<dim3(nb), dim3(256), 0, stream>>>(slabs, S, cnt, out, N, nb);
}

// Round 9
// 32.342 us; speedup vs baseline: 2.8293x; 1.2682x over previous
//
#include <hip/hip_runtime.h>

// SIMcLoss: x [8192, 256] fp32 -> scalar.
// loss = (||Xn^T Xn||_F^2 - n)/(n^2 - n) on the 256x256 Gram matrix.
// Two dispatches:
//   k_prep : one wave per row -> inv norms; zeroes ctrl words.
//   k_gram : bf16(RNE) MFMA Gram tiles (10 sym pairs x 16 K-chunks,
//            double-buffered LDS, 1 barrier/sub-chunk), coalesced slab
//            store, then per-pair ACQ_REL ticket (tid0-only fence!);
//            16th block of each pair reduces its 16 slabs (weight, square),
//            atomicAdd(S), global ticket writes the loss.
// Fence discipline (rounds 6/7 lesson): cross-block hand-off uses ONE
// single-thread device-scope fence per block, never per-thread fences,
// never bulk agent-scope data ops.
#define D 256
#define TILE 64
#define NPAIRS 10
#define CHUNK 512
#define NCHUNK 16
#define EPS 1e-8f

typedef __attribute__((ext_vector_type(8))) short bf16x8;
typedef __attribute__((ext_vector_type(4))) float f32x4;

__device__ __forceinline__ void pair_decode(int p, int& ta, int& tb) {
  if (p < 4)      { ta = 0; tb = p; }
  else if (p < 7) { ta = 1; tb = p - 3; }
  else if (p < 9) { ta = 2; tb = p - 5; }
  else            { ta = 3; tb = 3; }
}

// swizzled short-index into Xt[col][64 rows] (row-stride 64 shorts = 128 B).
// XOR bits 3..5 of row with g(col): b128 frag reads ~2-way, b64 writes 4-way.
__device__ __forceinline__ int swz(int col, int r) {
  int g = ((col >> 2) & 7) ^ ((col & 3) << 1);
  return col * 64 + (r ^ (g << 3));
}

// round-to-nearest-even fp32 -> bf16 (truncation would bias S)
__device__ __forceinline__ unsigned short rne_bf16(float f) {
  unsigned u = __float_as_uint(f);
  return (unsigned short)((u + 0x7fffu + ((u >> 16) & 1u)) >> 16);
}

// ---------------------------------------------------------------------------
// Kernel 1: row inverse norms (one wave per row) + zero ctrl words.
// ---------------------------------------------------------------------------
__global__ __launch_bounds__(256) void k_prep(
    const float* __restrict__ x, float* __restrict__ inv,
    float* __restrict__ ctrl, int N) {
  if (blockIdx.x == 0 && threadIdx.x < 16) ctrl[threadIdx.x] = 0.0f;
  int wave = (blockIdx.x * blockDim.x + threadIdx.x) >> 6;
  int lane = threadIdx.x & 63;
  if (wave >= N) return;
  const float4 v = reinterpret_cast<const float4*>(x + (size_t)wave * D)[lane];
  float s = v.x * v.x + v.y * v.y + v.z * v.z + v.w * v.w;
  #pragma unroll
  for (int o = 32; o > 0; o >>= 1) s += __shfl_xor(s, o);
  if (lane == 0) inv[wave] = 1.0f / fmaxf(sqrtf(s), EPS);
}

// ---------------------------------------------------------------------------
// Kernel 2: Gram tiles + in-kernel ticket-chained reduce.
// grid (NPAIRS, NCHUNK), 512 threads.
// ---------------------------------------------------------------------------
__global__ __launch_bounds__(512) void k_gram(
    const float* __restrict__ x, const float* __restrict__ inv,
    float* __restrict__ slabs, float* __restrict__ S,
    unsigned int* __restrict__ pair_cnt, unsigned int* __restrict__ gcnt,
    float* __restrict__ out, int N) {
  const int pair = blockIdx.x, chunk = blockIdx.y;
  int ta, tb; pair_decode(pair, ta, tb);
  const bool same = (ta == tb);
  const int row0 = chunk * CHUNK;
  const int tid = threadIdx.x;
  const int w = tid >> 6, lane = tid & 63;

  __shared__ short X[2][128 * 64];  // double-buffered [col][row] bf16 tile
  __shared__ float red[8];
  __shared__ unsigned int tkt;

  // ---- staging geometry: 4 rows x 4 cols micro-transpose per task ----
  const int lcb = same ? 4 : 5;                 // log2(col-blocks)
  const int ntask = 16 << lcb;                  // 256 or 512
  const bool active = tid < ntask;
  const int c0 = (tid & ((1 << lcb) - 1)) << 2; // LDS col base
  const int r0 = (active ? (tid >> lcb) : 0) << 2;
  const int gc0 = (c0 < TILE) ? ta * TILE + c0 : tb * TILE + (c0 - TILE);

  // MFMA decomposition: wave w owns 16x32 of the 64x64 tile
  const int i0 = (w >> 1) << 4;                 // 0,16,32,48
  const int j0 = (w & 1) << 5;                  // 0,32
  const int lm = lane & 15, lk = lane >> 4;
  const int bbase = same ? 0 : 64;

  f32x4 zero = {0.f, 0.f, 0.f, 0.f};
  f32x4 acc[2] = {zero, zero};

  float4 pv[4]; float4 piv;
  if (active) {
    piv = *reinterpret_cast<const float4*>(&inv[row0 + r0]);
    const float* xb = x + (size_t)(row0 + r0) * D + gc0;
    #pragma unroll
    for (int jj = 0; jj < 4; ++jj)
      pv[jj] = *reinterpret_cast<const float4*>(xb + (size_t)jj * D);
  }

  const int NSUB = CHUNK / 64;                  // 8
  for (int s = 0; s < NSUB; ++s) {
    short* Xb = X[s & 1];
    if (active) {
      const float ivv[4] = {piv.x, piv.y, piv.z, piv.w};
      unsigned short hh[4][4];
      #pragma unroll
      for (int jj = 0; jj < 4; ++jj) {
        const float vv[4] = {pv[jj].x, pv[jj].y, pv[jj].z, pv[jj].w};
        #pragma unroll
        for (int cc = 0; cc < 4; ++cc)
          hh[jj][cc] = rne_bf16(vv[cc] * ivv[jj]);
      }
      #pragma unroll
      for (int cc = 0; cc < 4; ++cc)
        *reinterpret_cast<ushort4*>(&Xb[swz(c0 + cc, r0)]) =
            make_ushort4(hh[0][cc], hh[1][cc], hh[2][cc], hh[3][cc]);
      if (s + 1 < NSUB) {                       // prefetch next sub-chunk
        const int nr0 = row0 + (s + 1) * 64 + r0;
        piv = *reinterpret_cast<const float4*>(&inv[nr0]);
        const float* xb = x + (size_t)nr0 * D + gc0;
        #pragma unroll
        for (int jj = 0; jj < 4; ++jj)
          pv[jj] = *reinterpret_cast<const float4*>(xb + (size_t)jj * D);
      }
    }
    __syncthreads();                            // one barrier per sub-chunk
    #pragma unroll
    for (int rr = 0; rr < 64; rr += 32) {
      const int rbase = rr + lk * 8;
      bf16x8 A  = *reinterpret_cast<const bf16x8*>(&Xb[swz(i0 + lm, rbase)]);
      bf16x8 B0 = *reinterpret_cast<const bf16x8*>(&Xb[swz(bbase + j0 + lm, rbase)]);
      bf16x8 B1 = *reinterpret_cast<const bf16x8*>(&Xb[swz(bbase + j0 + 16 + lm, rbase)]);
      acc[0] = __builtin_amdgcn_mfma_f32_16x16x32_bf16(A, B0, acc[0], 0, 0, 0);
      acc[1] = __builtin_amdgcn_mfma_f32_16x16x32_bf16(A, B1, acc[1], 0, 0, 0);
    }
  }

  // slab store (plain, coalesced); C/D: col = lane&15, row = (lane>>4)*4+reg
  float* slab = slabs + ((size_t)pair * NCHUNK + chunk) * (TILE * TILE);
  #pragma unroll
  for (int jt = 0; jt < 2; ++jt)
    #pragma unroll
    for (int rg = 0; rg < 4; ++rg)
      slab[(i0 + lk * 4 + rg) * TILE + (j0 + jt * 16 + lm)] = acc[jt][rg];

  // ---- per-pair ticket: tid0-ONLY fence (rounds 6/7 lesson) ----
  __syncthreads();                     // all waves' stores complete to L2
  if (tid == 0) {
    __threadfence();                   // one wave: writeback for other XCDs
    tkt = __hip_atomic_fetch_add(&pair_cnt[pair], 1u, __ATOMIC_ACQ_REL,
                                 __HIP_MEMORY_SCOPE_AGENT);
  }
  __syncthreads();
  if (tkt != (unsigned)(NCHUNK - 1)) return;    // not last of pair -> done

  // ---- last block of pair: reduce its 16 slabs ----
  const float* pbase = slabs + (size_t)pair * NCHUNK * (TILE * TILE);
  float part = 0.f;
  #pragma unroll
  for (int t4 = tid; t4 < (TILE * TILE / 4); t4 += 512) {  // 2 iters
    float tx = 0.f, ty = 0.f, tz = 0.f, tw = 0.f;
    #pragma unroll
    for (int c = 0; c < NCHUNK; ++c) {
      const float4 v = reinterpret_cast<const float4*>(
          pbase + (size_t)c * (TILE * TILE))[t4];
      tx += v.x; ty += v.y; tz += v.z; tw += v.w;
    }
    part += tx * tx + ty * ty + tz * tz + tw * tw;
  }
  part *= same ? 1.f : 2.f;
  #pragma unroll
  for (int o = 32; o > 0; o >>= 1) part += __shfl_xor(part, o);
  if (lane == 0) red[w] = part;
  __syncthreads();
  if (tid == 0) {
    float blk = 0.f;
    #pragma unroll
    for (int q = 0; q < 8; ++q) blk += red[q];
    atomicAdd(S, blk);
    __threadfence();
    unsigned int old = __hip_atomic_fetch_add(gcnt, 1u, __ATOMIC_ACQ_REL,
                                              __HIP_MEMORY_SCOPE_AGENT);
    if (old == (unsigned)(NPAIRS - 1)) {
      float Sv = __hip_atomic_load(S, __ATOMIC_RELAXED,
                                   __HIP_MEMORY_SCOPE_AGENT);
      float nf = (float)N;
      out[0] = (Sv - nf) / (nf * nf - nf);
    }
  }
}

extern "C" void kernel_launch(void* const* d_in, const int* in_sizes, int n_in,
                              void* d_out, int out_size, void* d_ws, size_t ws_size,
                              hipStream_t stream) {
  const float* x = (const float*)d_in[0];
  float* out = (float*)d_out;
  const int N = in_sizes[0] / D;       // 8192

  // ws layout (floats): inv[N] | ctrl[64]: S, gcnt, pair_cnt[10] | slabs
  float* inv = (float*)d_ws;
  float* ctrl = inv + N;
  float* S = ctrl;
  unsigned int* gcnt = (unsigned int*)(ctrl + 1);
  unsigned int* pair_cnt = (unsigned int*)(ctrl + 2);
  float* slabs = ctrl + 64;

  k_prep<<<dim3(N / 4), dim3(256), 0, stream>>>(x, inv, ctrl, N);
  k_gram<<<dim3(NPAIRS, NCHUNK), dim3(512), 0, stream>>>(
      x, inv, slabs, S, pair_cnt, gcnt, out, N);
}